// Round 1
// baseline (798.546 us; speedup 1.0000x reference)
//
#include <hip/hip_runtime.h>
#include <hip/hip_bf16.h>

// Problem constants (fixed-shape problem per reference).
#define N_TOT 131072
#define DIM   1024     // D
#define HID   512      // H
#define NCLS  2        // C

#define TILE_M 64      // rows per block
#define BK     64      // K-tile
#define LDA    72      // padded A row length (elements) -> 144 B row stride (16B-aligned, breaks pow2 banks)

typedef __attribute__((ext_vector_type(8))) short bf16x8;   // 8 bf16 = 4 VGPRs (MFMA A/B frag)
typedef __attribute__((ext_vector_type(4))) float f32x4;    // MFMA C/D frag

__device__ __forceinline__ void gld_lds16(const void* g, void* l) {
  // async global->LDS, 16B/lane; LDS dest = wave-uniform base + lane*16
  __builtin_amdgcn_global_load_lds((const __attribute__((address_space(1))) void*)g,
                                   (__attribute__((address_space(3))) void*)l, 16, 0, 0);
}

// ---------------- Kernel 1: W1 [D][H] fp32 -> W1t [H][D] bf16 ----------------
__global__ __launch_bounds__(256)
void w1_transpose_cast(const float* __restrict__ W1, __hip_bfloat16* __restrict__ W1t) {
  __shared__ float tile[32][33];
  const int tx = threadIdx.x, ty = threadIdx.y;
  const int h0 = blockIdx.x * 32, k0 = blockIdx.y * 32;
#pragma unroll
  for (int r = 0; r < 4; ++r) {
    int k = k0 + ty + r * 8, h = h0 + tx;
    tile[ty + r * 8][tx] = W1[(size_t)k * HID + h];
  }
  __syncthreads();
#pragma unroll
  for (int r = 0; r < 4; ++r) {
    int h = h0 + ty + r * 8, k = k0 + tx;
    W1t[(size_t)h * DIM + k] = __float2bfloat16(tile[tx][ty + r * 8]);
  }
}

// ---------------- Kernel 2: fused gate + GEMM1 + bias/relu + GEMM2 + b2 ----------------
// Block: 512 threads (8 waves), computes 64 rows x full H=512, then reduces to
// patch_logits[64][2] in the epilogue (fp32).
__global__ __launch_bounds__(512, 2)
void fused_main(const float* __restrict__ feat, const float* __restrict__ att,
                const __hip_bfloat16* __restrict__ W1t, const float* __restrict__ b1,
                const float* __restrict__ W2, const float* __restrict__ b2,
                float* __restrict__ patch_out) {
  __shared__ __hip_bfloat16 Alds[TILE_M * LDA];   // 9216 B, [m][k] padded
  __shared__ __hip_bfloat16 Blds[HID * BK];       // 65536 B, [n][k] row-major (global_load_lds order)
  __shared__ float hbuf[TILE_M][2];               // per-row logits partials

  const int tid  = threadIdx.x;
  const int lane = tid & 63;
  const int w    = tid >> 6;          // wave 0..7
  const int n0   = blockIdx.x * TILE_M;

  // A-staging role (fixed across K): row = tid>>3 (0..63), k-group = tid&7
  const int arow = tid >> 3;
  const int akg  = tid & 7;
  const float attv = att[n0 + arow];
  const float* featrow = feat + (size_t)(n0 + arow) * DIM + akg * 8;

  // B-staging: wave w stages Bt rows [w*64, w*64+64); chunk cc = 8 rows (64 lanes x 16B)
  const __hip_bfloat16* bsrc = W1t + (size_t)(w * 64 + (lane >> 3)) * DIM + (lane & 7) * 8;
  __hip_bfloat16* bdst = Blds + (size_t)(w * 8) * 512;  // 512 elems (1 KB) per chunk

  // MFMA geometry: wave covers row-tiles {wr*2, wr*2+1} x col-tiles {wc*8 .. wc*8+7}
  const int l15  = lane & 15;
  const int quad = lane >> 4;
  const int wr = w >> 2;   // 0..1
  const int wc = w & 3;    // 0..3

  f32x4 acc[2][8];
  const f32x4 zero = {0.f, 0.f, 0.f, 0.f};
#pragma unroll
  for (int i = 0; i < 2; ++i)
#pragma unroll
    for (int j = 0; j < 8; ++j) acc[i][j] = zero;

#pragma unroll 1
  for (int k0 = 0; k0 < DIM; k0 += BK) {
    __syncthreads();   // previous tile's LDS reads done
    // ---- stage B: 8 async 16B chunks per wave (full 512x64 bf16 tile) ----
#pragma unroll
    for (int cc = 0; cc < 8; ++cc)
      gld_lds16(bsrc + (size_t)cc * 8 * DIM + k0, bdst + cc * 512);
    // ---- stage A: fp32 load, gate by attention, cvt bf16, 16B LDS write ----
    {
      const float4 f0 = *(const float4*)(featrow + k0);
      const float4 f1 = *(const float4*)(featrow + k0 + 4);
      union { bf16x8 v; __hip_bfloat16 h[8]; } u;
      u.h[0] = __float2bfloat16(f0.x * attv);
      u.h[1] = __float2bfloat16(f0.y * attv);
      u.h[2] = __float2bfloat16(f0.z * attv);
      u.h[3] = __float2bfloat16(f0.w * attv);
      u.h[4] = __float2bfloat16(f1.x * attv);
      u.h[5] = __float2bfloat16(f1.y * attv);
      u.h[6] = __float2bfloat16(f1.z * attv);
      u.h[7] = __float2bfloat16(f1.w * attv);
      *(bf16x8*)(Alds + arow * LDA + akg * 8) = u.v;
    }
    __syncthreads();   // staging (vmcnt+lgkmcnt) drained
    // ---- compute: 2 k-halves x (2x8) MFMA tiles ----
#pragma unroll
    for (int kh = 0; kh < 2; ++kh) {
      bf16x8 afrag[2], bfrag[8];
#pragma unroll
      for (int i = 0; i < 2; ++i) {
        int row = (wr * 2 + i) * 16 + l15;                       // A[m=l15][k=quad*8+j]
        afrag[i] = *(const bf16x8*)(Alds + row * LDA + kh * 32 + quad * 8);
      }
#pragma unroll
      for (int j = 0; j < 8; ++j) {
        int brow = (wc * 8 + j) * 16 + l15;                      // B[k=quad*8+j][n=l15] via Bt[n][k]
        bfrag[j] = *(const bf16x8*)(Blds + brow * BK + kh * 32 + quad * 8);
      }
#pragma unroll
      for (int i = 0; i < 2; ++i)
#pragma unroll
        for (int j = 0; j < 8; ++j)
          acc[i][j] = __builtin_amdgcn_mfma_f32_16x16x32_bf16(afrag[i], bfrag[j], acc[i][j], 0, 0, 0);
    }
  }

  // ---- epilogue: h = relu(acc + b1); patch_logits = h @ W2 + b2 (all fp32) ----
  __syncthreads();
  if (tid < TILE_M * 2) ((float*)hbuf)[tid] = 0.f;
  __syncthreads();

  float p[2][4][2];
#pragma unroll
  for (int i = 0; i < 2; ++i)
#pragma unroll
    for (int r = 0; r < 4; ++r) { p[i][r][0] = 0.f; p[i][r][1] = 0.f; }

#pragma unroll
  for (int j = 0; j < 8; ++j) {
    int col = (wc * 8 + j) * 16 + l15;       // h-column this lane owns in tile j
    float bb  = b1[col];
    float w20 = W2[col * 2 + 0];
    float w21 = W2[col * 2 + 1];
#pragma unroll
    for (int i = 0; i < 2; ++i)
#pragma unroll
      for (int r = 0; r < 4; ++r) {
        float v = acc[i][j][r] + bb;
        v = fmaxf(v, 0.f);
        p[i][r][0] += v * w20;
        p[i][r][1] += v * w21;
      }
  }
  // reduce over the 16 columns held by lanes sharing a quad (C/D: row=quad*4+r, col=l15)
#pragma unroll
  for (int m = 1; m < 16; m <<= 1)
#pragma unroll
    for (int i = 0; i < 2; ++i)
#pragma unroll
      for (int r = 0; r < 4; ++r) {
        p[i][r][0] += __shfl_xor(p[i][r][0], m, 64);
        p[i][r][1] += __shfl_xor(p[i][r][1], m, 64);
      }
  if (l15 == 0) {
#pragma unroll
    for (int i = 0; i < 2; ++i)
#pragma unroll
      for (int r = 0; r < 4; ++r) {
        int row = (wr * 2 + i) * 16 + quad * 4 + r;
        atomicAdd(&hbuf[row][0], p[i][r][0]);   // 4 col-group waves combine
        atomicAdd(&hbuf[row][1], p[i][r][1]);
      }
  }
  __syncthreads();
  if (tid < TILE_M * 2) {
    int row = tid >> 1, c = tid & 1;
    patch_out[(size_t)(n0 + row) * 2 + c] = hbuf[row][c] + b2[c];
  }
}

// ---------------- Kernel 3: ragged per-bag segment sum ----------------
__global__ __launch_bounds__(256)
void bag_logits(const float* __restrict__ patch, const int* __restrict__ bag_sizes,
                float* __restrict__ logits) {
  const int b = blockIdx.x;
  long off = 0;
  for (int i = 0; i < b; ++i) off += bag_sizes[i];
  const int sz = bag_sizes[b];
  float s0 = 0.f, s1 = 0.f;
  const float2* p = (const float2*)patch + off;
  for (int i = threadIdx.x; i < sz; i += 256) {
    float2 v = p[i];
    s0 += v.x; s1 += v.y;
  }
#pragma unroll
  for (int m = 1; m < 64; m <<= 1) {
    s0 += __shfl_xor(s0, m, 64);
    s1 += __shfl_xor(s1, m, 64);
  }
  __shared__ float r0[4], r1[4];
  const int wv = threadIdx.x >> 6;
  if ((threadIdx.x & 63) == 0) { r0[wv] = s0; r1[wv] = s1; }
  __syncthreads();
  if (threadIdx.x == 0) {
    float t0 = 0.f, t1 = 0.f;
    for (int i = 0; i < 4; ++i) { t0 += r0[i]; t1 += r1[i]; }
    logits[b * 2 + 0] = t0;
    logits[b * 2 + 1] = t1;
  }
}

extern "C" void kernel_launch(void* const* d_in, const int* in_sizes, int n_in,
                              void* d_out, int out_size, void* d_ws, size_t ws_size,
                              hipStream_t stream) {
  const float* feat = (const float*)d_in[0];   // [N, D]
  const float* att  = (const float*)d_in[1];   // [N, 1]
  const int*   bags = (const int*)d_in[2];     // [B]
  const float* W1   = (const float*)d_in[3];   // [D, H]
  const float* b1   = (const float*)d_in[4];   // [H]
  const float* W2   = (const float*)d_in[5];   // [H, C]
  const float* b2   = (const float*)d_in[6];   // [C]
  float* out = (float*)d_out;                  // [B*C logits][N*C patch_logits]

  const int B = in_sizes[2];
  float* patch = out + (size_t)B * NCLS;
  __hip_bfloat16* W1t = (__hip_bfloat16*)d_ws;  // 512*1024*2 = 1 MB scratch

  w1_transpose_cast<<<dim3(HID / 32, DIM / 32), dim3(32, 8), 0, stream>>>(W1, W1t);
  fused_main<<<N_TOT / TILE_M, 512, 0, stream>>>(feat, att, W1t, b1, W2, b2, patch);
  bag_logits<<<B, 256, 0, stream>>>(patch, bags, out);
}

// Round 2
// 771.175 us; speedup vs baseline: 1.0355x; 1.0355x over previous
//
#include <hip/hip_runtime.h>
#include <hip/hip_bf16.h>

// Problem constants (fixed-shape problem per reference).
#define N_TOT 131072
#define DIM   1024     // D
#define HID   512      // H
#define NCLS  2        // C

#define TILE_M 64      // rows per block
#define BK     64      // K-tile
#define LDA    72      // padded A row length (elements); 144 B row stride -> A-frag reads 2-way (free)

typedef __attribute__((ext_vector_type(8))) short bf16x8;   // 8 bf16 = 4 VGPRs (MFMA A/B frag)
typedef __attribute__((ext_vector_type(4))) float f32x4;    // MFMA C/D frag

__device__ __forceinline__ void gld_lds16(const void* g, void* l) {
  // async global->LDS, 16B/lane; LDS dest = wave-uniform base + lane*16
  __builtin_amdgcn_global_load_lds((const __attribute__((address_space(1))) void*)g,
                                   (__attribute__((address_space(3))) void*)l, 16, 0, 0);
}

// ---------------- Kernel 1: W1 [D][H] fp32 -> W1s [H][D] bf16, k-group XOR-swizzled ----
// Within each 64-element K-block, the 8-element group g of row h is stored at
// group g ^ (h&7). This makes the B-fragment ds_read_b128 in fused_main
// conflict-free (quad lanes spread over all 8 4-bank groups) while keeping the
// global_load_lds staging source perfectly contiguous.
__global__ __launch_bounds__(256)
void w1_transpose_cast(const float* __restrict__ W1, __hip_bfloat16* __restrict__ W1s) {
  __shared__ float tile[32][33];
  const int tx = threadIdx.x, ty = threadIdx.y;
  const int h0 = blockIdx.x * 32, k0 = blockIdx.y * 32;
#pragma unroll
  for (int r = 0; r < 4; ++r) {
    int k = k0 + ty + r * 8, h = h0 + tx;
    tile[ty + r * 8][tx] = W1[(size_t)k * HID + h];
  }
  __syncthreads();
#pragma unroll
  for (int r = 0; r < 4; ++r) {
    int h = h0 + ty + r * 8, k = k0 + tx;
    int ksw = k ^ ((h & 7) << 3);   // XOR bits 3..5: stays within the 64-elem block
    W1s[(size_t)h * DIM + ksw] = __float2bfloat16(tile[tx][ty + r * 8]);
  }
}

// ---------------- Kernel 2: fused gate + GEMM1 + bias/relu + GEMM2 + b2 ----------------
// Block: 512 threads (8 waves), computes 64 rows x full H=512, then reduces to
// patch_logits[64][2] in the epilogue (fp32).
__global__ __launch_bounds__(512, 2)
void fused_main(const float* __restrict__ feat, const float* __restrict__ att,
                const __hip_bfloat16* __restrict__ W1s, const float* __restrict__ b1,
                const float* __restrict__ W2, const float* __restrict__ b2,
                float* __restrict__ patch_out) {
  __shared__ __hip_bfloat16 Alds[TILE_M * LDA];   // 9216 B, [m][k] padded
  __shared__ __hip_bfloat16 Blds[HID * BK];       // 65536 B, [n][k] row-major, k-groups swizzled
  __shared__ float hbuf[TILE_M][2];               // per-row logits partials

  const int tid  = threadIdx.x;
  const int lane = tid & 63;
  const int w    = tid >> 6;          // wave 0..7
  const int n0   = blockIdx.x * TILE_M;

  // A-staging role (fixed across K): row = tid>>3 (0..63), k-group = tid&7
  const int arow = tid >> 3;
  const int akg  = tid & 7;
  const float attv = att[n0 + arow];
  const float* featrow = feat + (size_t)(n0 + arow) * DIM + akg * 8;

  // B-staging: wave w stages W1s rows [w*64, w*64+64); chunk cc = 8 rows (64 lanes x 16B)
  const __hip_bfloat16* bsrc = W1s + (size_t)(w * 64 + (lane >> 3)) * DIM + (lane & 7) * 8;
  __hip_bfloat16* bdst = Blds + (size_t)(w * 8) * 512;  // 512 elems (1 KB) per chunk

  // MFMA geometry: wave covers row-tiles {wr*2, wr*2+1} x col-tiles {wc*8 .. wc*8+7}
  const int l15  = lane & 15;
  const int quad = lane >> 4;
  const int wr = w >> 2;   // 0..1
  const int wc = w & 3;    // 0..3
  const int bsw = (l15 & 7) << 3;   // B k-group un-swizzle offset (elements)

  f32x4 acc[2][8];
  const f32x4 zero = {0.f, 0.f, 0.f, 0.f};
#pragma unroll
  for (int i = 0; i < 2; ++i)
#pragma unroll
    for (int j = 0; j < 8; ++j) acc[i][j] = zero;

#pragma unroll 1
  for (int k0 = 0; k0 < DIM; k0 += BK) {
    __syncthreads();   // previous tile's LDS reads done
    // ---- stage B: 8 async 16B chunks per wave (full 512x64 bf16 tile) ----
#pragma unroll
    for (int cc = 0; cc < 8; ++cc)
      gld_lds16(bsrc + (size_t)cc * 8 * DIM + k0, bdst + cc * 512);
    // ---- stage A: fp32 load, gate by attention, cvt bf16, 16B LDS write ----
    {
      const float4 f0 = *(const float4*)(featrow + k0);
      const float4 f1 = *(const float4*)(featrow + k0 + 4);
      union { bf16x8 v; __hip_bfloat16 h[8]; } u;
      u.h[0] = __float2bfloat16(f0.x * attv);
      u.h[1] = __float2bfloat16(f0.y * attv);
      u.h[2] = __float2bfloat16(f0.z * attv);
      u.h[3] = __float2bfloat16(f0.w * attv);
      u.h[4] = __float2bfloat16(f1.x * attv);
      u.h[5] = __float2bfloat16(f1.y * attv);
      u.h[6] = __float2bfloat16(f1.z * attv);
      u.h[7] = __float2bfloat16(f1.w * attv);
      *(bf16x8*)(Alds + arow * LDA + akg * 8) = u.v;
    }
    __syncthreads();   // staging (vmcnt+lgkmcnt) drained
    // ---- compute: 2 k-halves x (2x8) MFMA tiles ----
#pragma unroll
    for (int kh = 0; kh < 2; ++kh) {
      bf16x8 afrag[2], bfrag[8];
#pragma unroll
      for (int i = 0; i < 2; ++i) {
        int row = (wr * 2 + i) * 16 + l15;                       // A[m=l15][k=quad*8+j]
        afrag[i] = *(const bf16x8*)(Alds + row * LDA + kh * 32 + quad * 8);
      }
      const int gbase = (kh * 4 + quad) << 3;                    // wanted k-group offset
#pragma unroll
      for (int j = 0; j < 8; ++j) {
        int brow = (wc * 8 + j) * 16 + l15;                      // B[k][n=l15] via W1s[n][k]
        bfrag[j] = *(const bf16x8*)(Blds + brow * BK + (gbase ^ bsw));
      }
#pragma unroll
      for (int i = 0; i < 2; ++i)
#pragma unroll
        for (int j = 0; j < 8; ++j)
          acc[i][j] = __builtin_amdgcn_mfma_f32_16x16x32_bf16(afrag[i], bfrag[j], acc[i][j], 0, 0, 0);
    }
  }

  // ---- epilogue: h = relu(acc + b1); patch_logits = h @ W2 + b2 (all fp32) ----
  __syncthreads();
  if (tid < TILE_M * 2) ((float*)hbuf)[tid] = 0.f;
  __syncthreads();

  float p[2][4][2];
#pragma unroll
  for (int i = 0; i < 2; ++i)
#pragma unroll
    for (int r = 0; r < 4; ++r) { p[i][r][0] = 0.f; p[i][r][1] = 0.f; }

#pragma unroll
  for (int j = 0; j < 8; ++j) {
    int col = (wc * 8 + j) * 16 + l15;       // h-column this lane owns in tile j
    float bb  = b1[col];
    float w20 = W2[col * 2 + 0];
    float w21 = W2[col * 2 + 1];
#pragma unroll
    for (int i = 0; i < 2; ++i)
#pragma unroll
      for (int r = 0; r < 4; ++r) {
        float v = acc[i][j][r] + bb;
        v = fmaxf(v, 0.f);
        p[i][r][0] += v * w20;
        p[i][r][1] += v * w21;
      }
  }
  // reduce over the 16 columns held by lanes sharing a quad (C/D: row=quad*4+r, col=l15)
#pragma unroll
  for (int m = 1; m < 16; m <<= 1)
#pragma unroll
    for (int i = 0; i < 2; ++i)
#pragma unroll
      for (int r = 0; r < 4; ++r) {
        p[i][r][0] += __shfl_xor(p[i][r][0], m, 64);
        p[i][r][1] += __shfl_xor(p[i][r][1], m, 64);
      }
  if (l15 == 0) {
#pragma unroll
    for (int i = 0; i < 2; ++i)
#pragma unroll
      for (int r = 0; r < 4; ++r) {
        int row = (wr * 2 + i) * 16 + quad * 4 + r;
        atomicAdd(&hbuf[row][0], p[i][r][0]);   // 4 col-group waves combine
        atomicAdd(&hbuf[row][1], p[i][r][1]);
      }
  }
  __syncthreads();
  if (tid < TILE_M * 2) {
    int row = tid >> 1, c = tid & 1;
    patch_out[(size_t)(n0 + row) * 2 + c] = hbuf[row][c] + b2[c];
  }
}

// ---------------- Kernel 3: ragged per-bag segment sum ----------------
__global__ __launch_bounds__(256)
void bag_logits(const float* __restrict__ patch, const int* __restrict__ bag_sizes,
                float* __restrict__ logits) {
  const int b = blockIdx.x;
  long off = 0;
  for (int i = 0; i < b; ++i) off += bag_sizes[i];
  const int sz = bag_sizes[b];
  float s0 = 0.f, s1 = 0.f;
  const float2* p = (const float2*)patch + off;
  for (int i = threadIdx.x; i < sz; i += 256) {
    float2 v = p[i];
    s0 += v.x; s1 += v.y;
  }
#pragma unroll
  for (int m = 1; m < 64; m <<= 1) {
    s0 += __shfl_xor(s0, m, 64);
    s1 += __shfl_xor(s1, m, 64);
  }
  __shared__ float r0[4], r1[4];
  const int wv = threadIdx.x >> 6;
  if ((threadIdx.x & 63) == 0) { r0[wv] = s0; r1[wv] = s1; }
  __syncthreads();
  if (threadIdx.x == 0) {
    float t0 = 0.f, t1 = 0.f;
    for (int i = 0; i < 4; ++i) { t0 += r0[i]; t1 += r1[i]; }
    logits[b * 2 + 0] = t0;
    logits[b * 2 + 1] = t1;
  }
}

extern "C" void kernel_launch(void* const* d_in, const int* in_sizes, int n_in,
                              void* d_out, int out_size, void* d_ws, size_t ws_size,
                              hipStream_t stream) {
  const float* feat = (const float*)d_in[0];   // [N, D]
  const float* att  = (const float*)d_in[1];   // [N, 1]
  const int*   bags = (const int*)d_in[2];     // [B]
  const float* W1   = (const float*)d_in[3];   // [D, H]
  const float* b1   = (const float*)d_in[4];   // [H]
  const float* W2   = (const float*)d_in[5];   // [H, C]
  const float* b2   = (const float*)d_in[6];   // [C]
  float* out = (float*)d_out;                  // [B*C logits][N*C patch_logits]

  const int B = in_sizes[2];
  float* patch = out + (size_t)B * NCLS;
  __hip_bfloat16* W1s = (__hip_bfloat16*)d_ws;  // 512*1024*2 = 1 MB scratch

  w1_transpose_cast<<<dim3(HID / 32, DIM / 32), dim3(32, 8), 0, stream>>>(W1, W1s);
  fused_main<<<N_TOT / TILE_M, 512, 0, stream>>>(feat, att, W1s, b1, W2, b2, patch);
  bag_logits<<<B, 256, 0, stream>>>(patch, bags, out);
}